// Round 1
// baseline (50.582 us; speedup 1.0000x reference)
//
#include <hip/hip_runtime.h>
#include <math.h>

#define PN 256
#define BN 1024
#define AN 15
#define NBIN 36

__device__ __forceinline__ int wrap36(int v) {
    // python-style modulo for v in roughly [-40, 80)
    v %= NBIN;
    if (v < 0) v += NBIN;
    return v;
}

__device__ __forceinline__ void crw(float t, float w[4]) {
    float t2 = t * t;
    float t3 = t2 * t;
    w[0] = -0.5f * t3 + t2 - 0.5f * t;
    w[1] =  1.5f * t3 - 2.5f * t2 + 1.0f;
    w[2] = -1.5f * t3 + 2.0f * t2 + 0.5f * t;
    w[3] =  0.5f * t3 - 0.5f * t2;
}

__device__ __forceinline__ void cross3(const float a[3], const float b[3], float o[3]) {
    o[0] = a[1] * b[2] - a[2] * b[1];
    o[1] = a[2] * b[0] - a[0] * b[2];
    o[2] = a[0] * b[1] - a[1] * b[0];
}

__device__ __forceinline__ float dot3(const float a[3], const float b[3]) {
    return a[0] * b[0] + a[1] * b[1] + a[2] * b[2];
}

__global__ __launch_bounds__(256) void bb_torsion_kernel(
    const float* __restrict__ coords,        // (P, B*A, 3)
    const int*   __restrict__ off,           // (P, B)
    const int*   __restrict__ btype,         // (P, B)
    const int*   __restrict__ conn,          // (P, B, 2, 2)
    const int*   __restrict__ dsc,           // (NBT, 2, 4)
    const int*   __restrict__ rama_tbl_ind,  // (NBT, 2)
    const int*   __restrict__ upper_conn,    // (NBT,)
    const int*   __restrict__ is_pro,        // (NBT,)
    const int*   __restrict__ tor_atoms,     // (NBT, 3, 4, 3)
    const float* __restrict__ rama_tables,   // (40, 36, 36)
    const float* __restrict__ omega_tables,  // (2, 36)
    const float* __restrict__ rama_params,   // (40, 4)
    const float* __restrict__ omega_params,  // (2, 2)
    float*       __restrict__ out)           // (2, P)
{
    const int p  = blockIdx.x >> 2;                       // pose
    const int b  = ((blockIdx.x & 3) << 8) | threadIdx.x; // block within pose
    const int pb = p * BN + b;

    const int  bt_raw = btype[pb];
    const bool real   = bt_raw >= 0;
    const int  btc    = real ? bt_raw : 0;
    const int  off_pb = off[pb];
    const float* cp   = coords + (size_t)p * (BN * AN) * 3;

    float dih[3];
    bool  tv[3];

    #pragma unroll
    for (int t = 0; t < 3; ++t) {
        float pts[4][3];
        bool  valid = true;
        #pragma unroll
        for (int at = 0; at < 4; ++at) {
            const int* ta = tor_atoms + (((btc * 3 + t) * 4 + at) * 3);
            const int a_ind   = ta[0];
            const int c_ind   = ta[1];
            const int n_bonds = ta[2];
            int  g;
            bool va;
            if (a_ind >= 0) {
                g  = off_pb + a_ind;
                va = true;
            } else {
                const int cc        = c_ind > 0 ? c_ind : 0;
                const int nbr_block = conn[pb * 4 + cc * 2 + 0];
                const int nbr_conn  = conn[pb * 4 + cc * 2 + 1];
                const int nb        = nbr_block > 0 ? nbr_block : 0;
                int nbt = btype[p * BN + nb];
                if (nbt < 0) nbt = 0;
                const int noff = off[p * BN + nb];
                const int ncc  = nbr_conn > 0 ? nbr_conn : 0;
                const int nbb  = n_bonds > 0 ? n_bonds : 0;
                const int ds   = dsc[(nbt * 2 + ncc) * 4 + nbb];
                g  = noff + ds;
                va = (c_ind >= 0) && (nbr_block >= 0) && (ds >= 0);
            }
            valid = valid && va;
            int gc = g > 0 ? g : 0;
            if (gc > BN * AN - 1) gc = BN * AN - 1;  // safety clamp
            const float* c3 = cp + (size_t)gc * 3;
            pts[at][0] = c3[0];
            pts[at][1] = c3[1];
            pts[at][2] = c3[2];
        }
        tv[t] = valid && real;

        float b1[3], b2[3], b3[3];
        #pragma unroll
        for (int k = 0; k < 3; ++k) {
            b1[k] = pts[1][k] - pts[0][k];
            b2[k] = pts[2][k] - pts[1][k];
            b3[k] = pts[3][k] - pts[2][k];
        }
        float n1[3], n2[3], b2n[3], m1[3];
        cross3(b1, b2, n1);
        cross3(b2, b3, n2);
        const float inv = 1.0f / sqrtf(dot3(b2, b2));
        #pragma unroll
        for (int k = 0; k < 3; ++k) b2n[k] = b2[k] * inv;
        cross3(n1, b2n, m1);
        dih[t] = atan2f(dot3(m1, n2), dot3(n1, n2));
    }

    // ---- rama ----
    int uc = upper_conn[btc];
    if (uc < 0) uc = 0;
    const int nxt  = conn[pb * 4 + uc * 2 + 0];
    const int nb2  = nxt > 0 ? nxt : 0;
    int nbt2 = btype[p * BN + nb2];
    if (nbt2 < 0) nbt2 = 0;
    const int ipn = (nxt >= 0) ? is_pro[nbt2] : 0;
    const int ri  = rama_tbl_ind[btc * 2 + ipn];

    const float* rp = rama_params + ri * 4;
    const float x = (dih[0] - rp[0]) / rp[2];
    const float y = (dih[1] - rp[1]) / rp[3];
    const float ix0 = floorf(x);
    const float iy0 = floorf(y);
    const float fx = x - ix0;
    const float fy = y - iy0;
    const int ix = (int)ix0;
    const int iy = (int)iy0;

    float wx[4], wy[4];
    crw(fx, wx);
    crw(fy, wy);

    int xs[4], ys[4];
    #pragma unroll
    for (int i = 0; i < 4; ++i) {
        xs[i] = wrap36(ix - 1 + i);
        ys[i] = wrap36(iy - 1 + i);
    }

    const float* rt = rama_tables + (size_t)ri * NBIN * NBIN;
    float er = 0.0f;
    #pragma unroll
    for (int i = 0; i < 4; ++i) {
        float rowv = 0.0f;
        const float* rrow = rt + xs[i] * NBIN;
        #pragma unroll
        for (int j = 0; j < 4; ++j) rowv += wy[j] * rrow[ys[j]];
        er += wx[i] * rowv;
    }
    float r_contrib = (tv[0] && tv[1]) ? er : 0.0f;

    // ---- omega ----
    const int oi = is_pro[btc];
    const float* op = omega_params + oi * 2;
    const float z = (dih[2] - op[0]) / op[1];
    const float iz0 = floorf(z);
    const float fz = z - iz0;
    const int iz = (int)iz0;
    float wz[4];
    crw(fz, wz);
    const float* ot = omega_tables + oi * NBIN;
    float eo = 0.0f;
    #pragma unroll
    for (int i = 0; i < 4; ++i) eo += wz[i] * ot[wrap36(iz - 1 + i)];
    float o_contrib = tv[2] ? eo : 0.0f;

    // ---- reduce: wave64 shuffle, then across 4 waves via LDS ----
    float r = r_contrib;
    float o = o_contrib;
    #pragma unroll
    for (int d = 32; d > 0; d >>= 1) {
        r += __shfl_down(r, d);
        o += __shfl_down(o, d);
    }
    __shared__ float sr[4], so[4];
    const int wid = threadIdx.x >> 6;
    if ((threadIdx.x & 63) == 0) {
        sr[wid] = r;
        so[wid] = o;
    }
    __syncthreads();
    if (threadIdx.x == 0) {
        const float R = sr[0] + sr[1] + sr[2] + sr[3];
        const float O = so[0] + so[1] + so[2] + so[3];
        atomicAdd(&out[p], R);
        atomicAdd(&out[PN + p], O);
    }
}

extern "C" void kernel_launch(void* const* d_in, const int* in_sizes, int n_in,
                              void* d_out, int out_size, void* d_ws, size_t ws_size,
                              hipStream_t stream) {
    const float* coords        = (const float*)d_in[0];
    const int*   off           = (const int*)d_in[1];
    const int*   btype         = (const int*)d_in[2];
    const int*   conn          = (const int*)d_in[3];
    const int*   dsc           = (const int*)d_in[4];
    const int*   rama_tbl_ind  = (const int*)d_in[5];
    const int*   upper_conn    = (const int*)d_in[6];
    const int*   is_pro        = (const int*)d_in[7];
    const int*   tor_atoms     = (const int*)d_in[8];
    const float* rama_tables   = (const float*)d_in[9];
    const float* omega_tables  = (const float*)d_in[10];
    const float* rama_params   = (const float*)d_in[11];
    const float* omega_params  = (const float*)d_in[12];
    float* out = (float*)d_out;

    // out is poisoned once before timing and never re-poisoned between
    // replays; we accumulate with atomics, so zero it every call.
    hipMemsetAsync(d_out, 0, (size_t)out_size * sizeof(float), stream);

    dim3 grid(PN * (BN / 256));  // 1024 blocks: 4 per pose
    dim3 block(256);
    bb_torsion_kernel<<<grid, block, 0, stream>>>(
        coords, off, btype, conn, dsc, rama_tbl_ind, upper_conn, is_pro,
        tor_atoms, rama_tables, omega_tables, rama_params, omega_params, out);
}

// Round 3
// 39.420 us; speedup vs baseline: 1.2831x; 1.2831x over previous
//
#include <hip/hip_runtime.h>
#include <math.h>

#define PN 256
#define BN 1024
#define AN 15
#define NBIN 36
#define RPB 256                 // residues per block
#define STAGE_DW (RPB * AN * 3) // 11520 dwords = 46080 B
#define STAGE_V4 (STAGE_DW / 4) // 2880 float4 (NOT divisible by 256!)

__device__ __forceinline__ int wrap36(int v) {
    v %= NBIN;
    if (v < 0) v += NBIN;
    return v;
}

__device__ __forceinline__ void crw(float t, float w[4]) {
    float t2 = t * t;
    float t3 = t2 * t;
    w[0] = -0.5f * t3 + t2 - 0.5f * t;
    w[1] =  1.5f * t3 - 2.5f * t2 + 1.0f;
    w[2] = -1.5f * t3 + 2.0f * t2 + 0.5f * t;
    w[3] =  0.5f * t3 - 0.5f * t2;
}

__device__ __forceinline__ void cross3(const float a[3], const float b[3], float o[3]) {
    o[0] = a[1] * b[2] - a[2] * b[1];
    o[1] = a[2] * b[0] - a[0] * b[2];
    o[2] = a[0] * b[1] - a[1] * b[0];
}

__device__ __forceinline__ float dot3(const float a[3], const float b[3]) {
    return a[0] * b[0] + a[1] * b[1] + a[2] * b[2];
}

__global__ __launch_bounds__(256) void bb_torsion_kernel(
    const float* __restrict__ coords,        // (P, B*A, 3)
    const int*   __restrict__ off,           // (P, B)
    const int*   __restrict__ btype,         // (P, B)
    const int*   __restrict__ conn,          // (P, B, 2, 2)
    const int*   __restrict__ dsc,           // (NBT, 2, 4)
    const int*   __restrict__ rama_tbl_ind,  // (NBT, 2)
    const int*   __restrict__ upper_conn,    // (NBT,)
    const int*   __restrict__ is_pro,        // (NBT,)
    const int*   __restrict__ tor_atoms,     // (NBT, 3, 4, 3)
    const float* __restrict__ rama_tables,   // (40, 36, 36)
    const float* __restrict__ omega_tables,  // (2, 36)
    const float* __restrict__ rama_params,   // (40, 4)
    const float* __restrict__ omega_params,  // (2, 2)
    float*       __restrict__ out)           // (2, P)
{
    const int p      = blockIdx.x >> 2;                   // pose
    const int rstart = (blockIdx.x & 3) << 8;             // first residue of block
    const int b      = rstart | threadIdx.x;              // residue within pose
    const int pb     = p * BN + b;

    const float* cp = coords + (size_t)p * (BN * AN) * 3;

    // ---- stage this block's coord slab into LDS (coalesced float4 stream) ----
    // STAGE_V4 = 2880 is NOT a multiple of 256: guarded stride loop (12 iters,
    // last one partially active).
    __shared__ float4 smem4[STAGE_V4];
    {
        const float4* src4 = (const float4*)(cp + (size_t)rstart * AN * 3);
        for (int i = threadIdx.x; i < STAGE_V4; i += 256)
            smem4[i] = src4[i];
    }
    __syncthreads();
    const float* smem = (const float*)smem4;
    const int base_atom = rstart * AN;

    const int  bt_raw = btype[pb];
    const bool real   = bt_raw >= 0;
    const int  btc    = real ? bt_raw : 0;
    const int  off_pb = off[pb];

    float dih[3];
    bool  tv[3];

    #pragma unroll
    for (int t = 0; t < 3; ++t) {
        float pts[4][3];
        bool  valid = true;
        #pragma unroll
        for (int at = 0; at < 4; ++at) {
            const int* ta = tor_atoms + (((btc * 3 + t) * 4 + at) * 3);
            const int a_ind   = ta[0];
            const int c_ind   = ta[1];
            const int n_bonds = ta[2];
            int  g;
            bool va;
            if (a_ind >= 0) {
                g  = off_pb + a_ind;
                va = true;
            } else {
                const int cc        = c_ind > 0 ? c_ind : 0;
                const int nbr_block = conn[pb * 4 + cc * 2 + 0];
                const int nbr_conn  = conn[pb * 4 + cc * 2 + 1];
                const int nb        = nbr_block > 0 ? nbr_block : 0;
                int nbt = btype[p * BN + nb];
                if (nbt < 0) nbt = 0;
                const int noff = off[p * BN + nb];
                const int ncc  = nbr_conn > 0 ? nbr_conn : 0;
                const int nbb  = n_bonds > 0 ? n_bonds : 0;
                const int ds   = dsc[(nbt * 2 + ncc) * 4 + nbb];
                g  = noff + ds;
                va = (c_ind >= 0) && (nbr_block >= 0) && (ds >= 0);
            }
            valid = valid && va;
            const int la = g - base_atom;   // atom index within staged slab
            if (la >= 0 && la < RPB * AN) {
                const float* s = smem + la * 3;
                pts[at][0] = s[0];
                pts[at][1] = s[1];
                pts[at][2] = s[2];
            } else {
                int gc = g > 0 ? g : 0;
                if (gc > BN * AN - 1) gc = BN * AN - 1;
                const float* c3 = cp + (size_t)gc * 3;
                pts[at][0] = c3[0];
                pts[at][1] = c3[1];
                pts[at][2] = c3[2];
            }
        }
        tv[t] = valid && real;

        float b1[3], b2[3], b3[3];
        #pragma unroll
        for (int k = 0; k < 3; ++k) {
            b1[k] = pts[1][k] - pts[0][k];
            b2[k] = pts[2][k] - pts[1][k];
            b3[k] = pts[3][k] - pts[2][k];
        }
        float n1[3], n2[3], b2n[3], m1[3];
        cross3(b1, b2, n1);
        cross3(b2, b3, n2);
        const float inv = 1.0f / sqrtf(dot3(b2, b2));
        #pragma unroll
        for (int k = 0; k < 3; ++k) b2n[k] = b2[k] * inv;
        cross3(n1, b2n, m1);
        dih[t] = atan2f(dot3(m1, n2), dot3(n1, n2));
    }

    // ---- rama ----
    int uc = upper_conn[btc];
    if (uc < 0) uc = 0;
    const int nxt  = conn[pb * 4 + uc * 2 + 0];
    const int nb2  = nxt > 0 ? nxt : 0;
    int nbt2 = btype[p * BN + nb2];
    if (nbt2 < 0) nbt2 = 0;
    const int ipn = (nxt >= 0) ? is_pro[nbt2] : 0;
    const int ri  = rama_tbl_ind[btc * 2 + ipn];

    const float* rp = rama_params + ri * 4;
    const float x = (dih[0] - rp[0]) / rp[2];
    const float y = (dih[1] - rp[1]) / rp[3];
    const float ix0 = floorf(x);
    const float iy0 = floorf(y);
    const float fx = x - ix0;
    const float fy = y - iy0;
    const int ix = (int)ix0;
    const int iy = (int)iy0;

    float wx[4], wy[4];
    crw(fx, wx);
    crw(fy, wy);

    int xs[4], ys[4];
    #pragma unroll
    for (int i = 0; i < 4; ++i) {
        xs[i] = wrap36(ix - 1 + i);
        ys[i] = wrap36(iy - 1 + i);
    }

    const float* rt = rama_tables + (size_t)ri * NBIN * NBIN;
    float er = 0.0f;
    #pragma unroll
    for (int i = 0; i < 4; ++i) {
        float rowv = 0.0f;
        const float* rrow = rt + xs[i] * NBIN;
        #pragma unroll
        for (int j = 0; j < 4; ++j) rowv += wy[j] * rrow[ys[j]];
        er += wx[i] * rowv;
    }
    float r_contrib = (tv[0] && tv[1]) ? er : 0.0f;

    // ---- omega ----
    const int oi = is_pro[btc];
    const float* op = omega_params + oi * 2;
    const float z = (dih[2] - op[0]) / op[1];
    const float iz0 = floorf(z);
    const float fz = z - iz0;
    const int iz = (int)iz0;
    float wz[4];
    crw(fz, wz);
    const float* ot = omega_tables + oi * NBIN;
    float eo = 0.0f;
    #pragma unroll
    for (int i = 0; i < 4; ++i) eo += wz[i] * ot[wrap36(iz - 1 + i)];
    float o_contrib = tv[2] ? eo : 0.0f;

    // ---- reduce: wave64 shuffle, then across 4 waves via LDS ----
    float r = r_contrib;
    float o = o_contrib;
    #pragma unroll
    for (int d = 32; d > 0; d >>= 1) {
        r += __shfl_down(r, d);
        o += __shfl_down(o, d);
    }
    __shared__ float sr[4], so[4];
    const int wid = threadIdx.x >> 6;
    if ((threadIdx.x & 63) == 0) {
        sr[wid] = r;
        so[wid] = o;
    }
    __syncthreads();
    if (threadIdx.x == 0) {
        const float R = sr[0] + sr[1] + sr[2] + sr[3];
        const float O = so[0] + so[1] + so[2] + so[3];
        atomicAdd(&out[p], R);
        atomicAdd(&out[PN + p], O);
    }
}

extern "C" void kernel_launch(void* const* d_in, const int* in_sizes, int n_in,
                              void* d_out, int out_size, void* d_ws, size_t ws_size,
                              hipStream_t stream) {
    const float* coords        = (const float*)d_in[0];
    const int*   off           = (const int*)d_in[1];
    const int*   btype         = (const int*)d_in[2];
    const int*   conn          = (const int*)d_in[3];
    const int*   dsc           = (const int*)d_in[4];
    const int*   rama_tbl_ind  = (const int*)d_in[5];
    const int*   upper_conn    = (const int*)d_in[6];
    const int*   is_pro        = (const int*)d_in[7];
    const int*   tor_atoms     = (const int*)d_in[8];
    const float* rama_tables   = (const float*)d_in[9];
    const float* omega_tables  = (const float*)d_in[10];
    const float* rama_params   = (const float*)d_in[11];
    const float* omega_params  = (const float*)d_in[12];
    float* out = (float*)d_out;

    // out is poisoned once before timing and never re-poisoned between
    // replays; we accumulate with atomics, so zero it every call.
    hipMemsetAsync(d_out, 0, (size_t)out_size * sizeof(float), stream);

    dim3 grid(PN * (BN / RPB));  // 1024 blocks: 4 per pose
    dim3 block(256);
    bb_torsion_kernel<<<grid, block, 0, stream>>>(
        coords, off, btype, conn, dsc, rama_tbl_ind, upper_conn, is_pro,
        tor_atoms, rama_tables, omega_tables, rama_params, omega_params, out);
}

// Round 4
// 32.927 us; speedup vs baseline: 1.5362x; 1.1972x over previous
//
#include <hip/hip_runtime.h>
#include <math.h>

#define PN 256
#define BN 1024
#define AN 15
#define NBIN 36
#define NBT 64
#define NRAMA 40
#define RPB 256
#define CSTRIDE 13   // 12 dwords (atoms 0..3 xyz) + 1 pad -> coprime with 32 banks

__device__ __forceinline__ int wrap36(int v) {
    v %= NBIN;
    if (v < 0) v += NBIN;
    return v;
}

__device__ __forceinline__ void crw(float t, float w[4]) {
    float t2 = t * t;
    float t3 = t2 * t;
    w[0] = -0.5f * t3 + t2 - 0.5f * t;
    w[1] =  1.5f * t3 - 2.5f * t2 + 1.0f;
    w[2] = -1.5f * t3 + 2.0f * t2 + 0.5f * t;
    w[3] =  0.5f * t3 - 0.5f * t2;
}

__device__ __forceinline__ void cross3(const float a[3], const float b[3], float o[3]) {
    o[0] = a[1] * b[2] - a[2] * b[1];
    o[1] = a[2] * b[0] - a[0] * b[2];
    o[2] = a[0] * b[1] - a[1] * b[0];
}

__device__ __forceinline__ float dot3(const float a[3], const float b[3]) {
    return a[0] * b[0] + a[1] * b[1] + a[2] * b[2];
}

__global__ __launch_bounds__(256) void bb_torsion_kernel(
    const float* __restrict__ coords,        // (P, B*A, 3)
    const int*   __restrict__ off,           // (P, B)
    const int*   __restrict__ btype,         // (P, B)
    const int*   __restrict__ conn,          // (P, B, 2, 2)
    const int*   __restrict__ dsc,           // (NBT, 2, 4)
    const int*   __restrict__ rama_tbl_ind,  // (NBT, 2)
    const int*   __restrict__ upper_conn,    // (NBT,)
    const int*   __restrict__ is_pro,        // (NBT,)
    const int*   __restrict__ tor_atoms,     // (NBT, 3, 4, 3)
    const float* __restrict__ rama_tables,   // (40, 36, 36)
    const float* __restrict__ omega_tables,  // (2, 36)
    const float* __restrict__ rama_params,   // (40, 4)
    const float* __restrict__ omega_params,  // (2, 2)
    float*       __restrict__ out)           // (2, P)
{
    const int tid    = threadIdx.x;
    const int p      = blockIdx.x >> 2;       // pose
    const int rstart = (blockIdx.x & 3) << 8; // first residue of this block
    const int b      = rstart + tid;          // residue within pose
    const int pb     = p * BN + b;

    const float* cp = coords + (size_t)p * (BN * AN) * 3;

    // ---- LDS: staged coords (atoms 0..3 per residue) + all small metadata ----
    __shared__ float cslab[RPB * CSTRIDE];    // 13312 B
    __shared__ int   s_ta[NBT * 36];          // 9216 B
    __shared__ int   s_dsc[NBT * 8];          // 2048 B
    __shared__ int   s_rti[NBT * 2];          // 512 B
    __shared__ int   s_uc[NBT];               // 256 B
    __shared__ int   s_ip[NBT];               // 256 B
    __shared__ float s_rp[NRAMA * 4];         // 640 B
    __shared__ float s_ot[2 * NBIN];          // 288 B
    __shared__ float s_op[4];                 // 16 B
    __shared__ float sr[4], so[4];

    // stage own residue's atoms 0..3 (12 consecutive dwords at off[b]*3)
    {
        const int off_r = off[pb];
        const float* src = cp + (size_t)off_r * 3;
        #pragma unroll
        for (int k = 0; k < 12; ++k) cslab[tid * CSTRIDE + k] = src[k];
    }
    for (int i = tid; i < NBT * 36; i += 256) s_ta[i] = tor_atoms[i];
    for (int i = tid; i < NBT * 8;  i += 256) s_dsc[i] = dsc[i];
    if (tid < NBT * 2)   s_rti[tid] = rama_tbl_ind[tid];
    if (tid < NBT)       { s_uc[tid] = upper_conn[tid]; s_ip[tid] = is_pro[tid]; }
    if (tid < NRAMA * 4) s_rp[tid] = rama_params[tid];
    if (tid < 2 * NBIN)  s_ot[tid] = omega_tables[tid];
    if (tid < 4)         s_op[tid] = omega_params[tid];
    __syncthreads();

    const int  bt_raw = btype[pb];
    const bool real   = bt_raw >= 0;
    const int  btc    = real ? bt_raw : 0;
    const int  off_pb = off[pb];

    float dih[3];
    bool  tv[3];

    #pragma unroll
    for (int t = 0; t < 3; ++t) {
        float pts[4][3];
        bool  valid = true;
        #pragma unroll
        for (int at = 0; at < 4; ++at) {
            const int tabase  = ((btc * 3 + t) * 4 + at) * 3;
            const int a_ind   = s_ta[tabase + 0];
            const int c_ind   = s_ta[tabase + 1];
            const int n_bonds = s_ta[tabase + 2];
            int  g, res, atom;
            bool va;
            if (a_ind >= 0) {
                g    = off_pb + a_ind;
                res  = b;          // own residue: always within staged window
                atom = a_ind;
                va   = true;
            } else {
                const int cc        = c_ind > 0 ? c_ind : 0;
                const int nbr_block = conn[pb * 4 + cc * 2 + 0];
                const int nbr_conn  = conn[pb * 4 + cc * 2 + 1];
                const int nb        = nbr_block > 0 ? nbr_block : 0;
                int nbt = btype[p * BN + nb];
                if (nbt < 0) nbt = 0;
                const int noff = off[p * BN + nb];
                const int ncc  = nbr_conn > 0 ? nbr_conn : 0;
                const int nbb  = n_bonds > 0 ? n_bonds : 0;
                const int ds   = s_dsc[(nbt * 2 + ncc) * 4 + nbb];
                g    = noff + ds;
                res  = nb;
                atom = ds;
                va   = (c_ind >= 0) && (nbr_block >= 0) && (ds >= 0);
            }
            valid = valid && va;
            const int lr = res - rstart;
            if (lr >= 0 && lr < RPB && atom >= 0 && atom < 4) {
                const float* s = cslab + lr * CSTRIDE + atom * 3;
                pts[at][0] = s[0];
                pts[at][1] = s[1];
                pts[at][2] = s[2];
            } else {
                int gc = g > 0 ? g : 0;
                if (gc > BN * AN - 1) gc = BN * AN - 1;
                const float* c3 = cp + (size_t)gc * 3;
                pts[at][0] = c3[0];
                pts[at][1] = c3[1];
                pts[at][2] = c3[2];
            }
        }
        tv[t] = valid && real;

        float b1[3], b2[3], b3[3];
        #pragma unroll
        for (int k = 0; k < 3; ++k) {
            b1[k] = pts[1][k] - pts[0][k];
            b2[k] = pts[2][k] - pts[1][k];
            b3[k] = pts[3][k] - pts[2][k];
        }
        float n1[3], n2[3], b2n[3], m1[3];
        cross3(b1, b2, n1);
        cross3(b2, b3, n2);
        const float inv = 1.0f / sqrtf(dot3(b2, b2));
        #pragma unroll
        for (int k = 0; k < 3; ++k) b2n[k] = b2[k] * inv;
        cross3(n1, b2n, m1);
        dih[t] = atan2f(dot3(m1, n2), dot3(n1, n2));
    }

    // ---- rama ----
    int uc = s_uc[btc];
    if (uc < 0) uc = 0;
    const int nxt = conn[pb * 4 + uc * 2 + 0];
    const int nb2 = nxt > 0 ? nxt : 0;
    int nbt2 = btype[p * BN + nb2];
    if (nbt2 < 0) nbt2 = 0;
    const int ipn = (nxt >= 0) ? s_ip[nbt2] : 0;
    const int ri  = s_rti[btc * 2 + ipn];

    const float* rp = s_rp + ri * 4;
    const float x = (dih[0] - rp[0]) / rp[2];
    const float y = (dih[1] - rp[1]) / rp[3];
    const float ix0 = floorf(x);
    const float iy0 = floorf(y);
    const float fx = x - ix0;
    const float fy = y - iy0;
    const int ix = (int)ix0;
    const int iy = (int)iy0;

    float wx[4], wy[4];
    crw(fx, wx);
    crw(fy, wy);

    int xs[4], ys[4];
    #pragma unroll
    for (int i = 0; i < 4; ++i) {
        xs[i] = wrap36(ix - 1 + i);
        ys[i] = wrap36(iy - 1 + i);
    }

    const float* rt = rama_tables + (size_t)ri * NBIN * NBIN;
    float er = 0.0f;
    #pragma unroll
    for (int i = 0; i < 4; ++i) {
        float rowv = 0.0f;
        const float* rrow = rt + xs[i] * NBIN;
        #pragma unroll
        for (int j = 0; j < 4; ++j) rowv += wy[j] * rrow[ys[j]];
        er += wx[i] * rowv;
    }
    float r_contrib = (tv[0] && tv[1]) ? er : 0.0f;

    // ---- omega ----
    const int oi = s_ip[btc];
    const float z = (dih[2] - s_op[oi * 2 + 0]) / s_op[oi * 2 + 1];
    const float iz0 = floorf(z);
    const float fz = z - iz0;
    const int iz = (int)iz0;
    float wz[4];
    crw(fz, wz);
    const float* ot = s_ot + oi * NBIN;
    float eo = 0.0f;
    #pragma unroll
    for (int i = 0; i < 4; ++i) eo += wz[i] * ot[wrap36(iz - 1 + i)];
    float o_contrib = tv[2] ? eo : 0.0f;

    // ---- reduce: wave64 shuffle, then across 4 waves via LDS ----
    float r = r_contrib;
    float o = o_contrib;
    #pragma unroll
    for (int d = 32; d > 0; d >>= 1) {
        r += __shfl_down(r, d);
        o += __shfl_down(o, d);
    }
    const int wid = tid >> 6;
    if ((tid & 63) == 0) {
        sr[wid] = r;
        so[wid] = o;
    }
    __syncthreads();
    if (tid == 0) {
        const float R = sr[0] + sr[1] + sr[2] + sr[3];
        const float O = so[0] + so[1] + so[2] + so[3];
        atomicAdd(&out[p], R);
        atomicAdd(&out[PN + p], O);
    }
}

extern "C" void kernel_launch(void* const* d_in, const int* in_sizes, int n_in,
                              void* d_out, int out_size, void* d_ws, size_t ws_size,
                              hipStream_t stream) {
    const float* coords        = (const float*)d_in[0];
    const int*   off           = (const int*)d_in[1];
    const int*   btype         = (const int*)d_in[2];
    const int*   conn          = (const int*)d_in[3];
    const int*   dsc           = (const int*)d_in[4];
    const int*   rama_tbl_ind  = (const int*)d_in[5];
    const int*   upper_conn    = (const int*)d_in[6];
    const int*   is_pro        = (const int*)d_in[7];
    const int*   tor_atoms     = (const int*)d_in[8];
    const float* rama_tables   = (const float*)d_in[9];
    const float* omega_tables  = (const float*)d_in[10];
    const float* rama_params   = (const float*)d_in[11];
    const float* omega_params  = (const float*)d_in[12];
    float* out = (float*)d_out;

    // out is poisoned once before timing and never re-poisoned between
    // replays; we accumulate with atomics, so zero it every call.
    hipMemsetAsync(d_out, 0, (size_t)out_size * sizeof(float), stream);

    // 1024 blocks = exactly 4 per CU; LDS ~27 KB keeps all 4 co-resident.
    dim3 grid(PN * (BN / RPB));
    dim3 block(256);
    bb_torsion_kernel<<<grid, block, 0, stream>>>(
        coords, off, btype, conn, dsc, rama_tbl_ind, upper_conn, is_pro,
        tor_atoms, rama_tables, omega_tables, rama_params, omega_params, out);
}

// Round 5
// 23.887 us; speedup vs baseline: 2.1175x; 1.3784x over previous
//
#include <hip/hip_runtime.h>
#include <math.h>

#define PN 256
#define BN 1024
#define AN 15
#define NBIN 36
#define NBT 64
#define NRAMA 40
#define CSTRIDE 13   // 12 dwords (atoms 0..3 xyz) + 1 pad -> coprime with 32 banks
#define CONNS 5      // 4 conn ints + 1 pad -> coprime with 32 banks

__device__ __forceinline__ int wrap36(int v) {
    v %= NBIN;
    if (v < 0) v += NBIN;
    return v;
}

__device__ __forceinline__ void crw(float t, float w[4]) {
    float t2 = t * t;
    float t3 = t2 * t;
    w[0] = -0.5f * t3 + t2 - 0.5f * t;
    w[1] =  1.5f * t3 - 2.5f * t2 + 1.0f;
    w[2] = -1.5f * t3 + 2.0f * t2 + 0.5f * t;
    w[3] =  0.5f * t3 - 0.5f * t2;
}

__device__ __forceinline__ void cross3(const float a[3], const float b[3], float o[3]) {
    o[0] = a[1] * b[2] - a[2] * b[1];
    o[1] = a[2] * b[0] - a[0] * b[2];
    o[2] = a[0] * b[1] - a[1] * b[0];
}

__device__ __forceinline__ float dot3(const float a[3], const float b[3]) {
    return a[0] * b[0] + a[1] * b[1] + a[2] * b[2];
}

__global__ __launch_bounds__(1024) void bb_torsion_kernel(
    const float* __restrict__ coords,        // (P, B*A, 3)
    const int*   __restrict__ off,           // (P, B)
    const int*   __restrict__ btype,         // (P, B)
    const int*   __restrict__ conn,          // (P, B, 2, 2)
    const int*   __restrict__ dsc,           // (NBT, 2, 4)
    const int*   __restrict__ rama_tbl_ind,  // (NBT, 2)
    const int*   __restrict__ upper_conn,    // (NBT,)
    const int*   __restrict__ is_pro,        // (NBT,)
    const int*   __restrict__ tor_atoms,     // (NBT, 3, 4, 3)
    const float* __restrict__ rama_tables,   // (40, 36, 36)
    const float* __restrict__ omega_tables,  // (2, 36)
    const float* __restrict__ rama_params,   // (40, 4)
    const float* __restrict__ omega_params,  // (2, 2)
    float*       __restrict__ out)           // (2, P)
{
    const int tid = threadIdx.x;
    const int p   = blockIdx.x;          // one block per pose
    const int pb  = p * BN + tid;        // this thread's residue

    const float* cp = coords + (size_t)p * (BN * AN) * 3;

    // ---- LDS: whole pose staged ----
    __shared__ float cslab[BN * CSTRIDE];   // 53248 B: atoms 0..3 xyz per residue
    __shared__ int   s_conn[BN * CONNS];    // 20480 B
    __shared__ int   s_bt[BN];              // 4096 B
    __shared__ int   s_off[BN];             // 4096 B
    __shared__ int   s_ta[NBT * 36];        // 9216 B
    __shared__ int   s_dsc[NBT * 8];        // 2048 B
    __shared__ int   s_rti[NBT * 2];        // 512 B
    __shared__ int   s_uc[NBT];             // 256 B
    __shared__ int   s_ip[NBT];             // 256 B
    __shared__ float s_rp[NRAMA * 4];       // 640 B
    __shared__ float s_ot[2 * NBIN];        // 288 B
    __shared__ float s_op[4];               // 16 B
    __shared__ float swr[16], swo[16];

    // ---- staging phase (all coalesced) ----
    const int off_r  = off[pb];
    const int bt_raw = btype[pb];
    s_off[tid] = off_r;
    s_bt[tid]  = bt_raw;
    {
        const float* src = cp + (size_t)off_r * 3;
        #pragma unroll
        for (int k = 0; k < 12; ++k) cslab[tid * CSTRIDE + k] = src[k];
    }
    #pragma unroll
    for (int k = 0; k < 4; ++k) s_conn[tid * CONNS + k] = conn[pb * 4 + k];
    for (int i = tid; i < NBT * 36; i += 1024) s_ta[i] = tor_atoms[i];
    if (tid < NBT * 8)   s_dsc[tid] = dsc[tid];
    if (tid < NBT * 2)   s_rti[tid] = rama_tbl_ind[tid];
    if (tid < NBT)       { s_uc[tid] = upper_conn[tid]; s_ip[tid] = is_pro[tid]; }
    if (tid < NRAMA * 4) s_rp[tid] = rama_params[tid];
    if (tid < 2 * NBIN)  s_ot[tid] = omega_tables[tid];
    if (tid < 4)         s_op[tid] = omega_params[tid];
    __syncthreads();

    const bool real = bt_raw >= 0;
    const int  btc  = real ? bt_raw : 0;

    float dih[3];
    bool  tv[3];

    #pragma unroll
    for (int t = 0; t < 3; ++t) {
        float pts[4][3];
        bool  valid = true;
        #pragma unroll
        for (int at = 0; at < 4; ++at) {
            const int tabase  = ((btc * 3 + t) * 4 + at) * 3;
            const int a_ind   = s_ta[tabase + 0];
            const int c_ind   = s_ta[tabase + 1];
            const int n_bonds = s_ta[tabase + 2];
            int  g, res, atom;
            bool va;
            if (a_ind >= 0) {
                g    = off_r + a_ind;
                res  = tid;
                atom = a_ind;
                va   = true;
            } else {
                const int cc        = c_ind > 0 ? c_ind : 0;
                const int nbr_block = s_conn[tid * CONNS + cc * 2 + 0];
                const int nbr_conn  = s_conn[tid * CONNS + cc * 2 + 1];
                const int nb        = nbr_block > 0 ? nbr_block : 0;
                int nbt = s_bt[nb];
                if (nbt < 0) nbt = 0;
                const int noff = s_off[nb];
                const int ncc  = nbr_conn > 0 ? nbr_conn : 0;
                const int nbb  = n_bonds > 0 ? n_bonds : 0;
                const int ds   = s_dsc[(nbt * 2 + ncc) * 4 + nbb];
                g    = noff + ds;
                res  = nb;
                atom = ds;
                va   = (c_ind >= 0) && (nbr_block >= 0) && (ds >= 0);
            }
            valid = valid && va;
            if (res >= 0 && res < BN && atom >= 0 && atom < 4) {
                const float* s = cslab + res * CSTRIDE + atom * 3;
                pts[at][0] = s[0];
                pts[at][1] = s[1];
                pts[at][2] = s[2];
            } else {
                int gc = g > 0 ? g : 0;
                if (gc > BN * AN - 1) gc = BN * AN - 1;
                const float* c3 = cp + (size_t)gc * 3;
                pts[at][0] = c3[0];
                pts[at][1] = c3[1];
                pts[at][2] = c3[2];
            }
        }
        tv[t] = valid && real;

        float b1[3], b2[3], b3[3];
        #pragma unroll
        for (int k = 0; k < 3; ++k) {
            b1[k] = pts[1][k] - pts[0][k];
            b2[k] = pts[2][k] - pts[1][k];
            b3[k] = pts[3][k] - pts[2][k];
        }
        float n1[3], n2[3], b2n[3], m1[3];
        cross3(b1, b2, n1);
        cross3(b2, b3, n2);
        const float inv = 1.0f / sqrtf(dot3(b2, b2));
        #pragma unroll
        for (int k = 0; k < 3; ++k) b2n[k] = b2[k] * inv;
        cross3(n1, b2n, m1);
        dih[t] = atan2f(dot3(m1, n2), dot3(n1, n2));
    }

    // ---- rama ----
    int uc = s_uc[btc];
    if (uc < 0) uc = 0;
    const int nxt = s_conn[tid * CONNS + uc * 2 + 0];
    const int nb2 = nxt > 0 ? nxt : 0;
    int nbt2 = s_bt[nb2];
    if (nbt2 < 0) nbt2 = 0;
    const int ipn = (nxt >= 0) ? s_ip[nbt2] : 0;
    const int ri  = s_rti[btc * 2 + ipn];

    const float* rp = s_rp + ri * 4;
    const float x = (dih[0] - rp[0]) / rp[2];
    const float y = (dih[1] - rp[1]) / rp[3];
    const float ix0 = floorf(x);
    const float iy0 = floorf(y);
    const float fx = x - ix0;
    const float fy = y - iy0;
    const int ix = (int)ix0;
    const int iy = (int)iy0;

    float wx[4], wy[4];
    crw(fx, wx);
    crw(fy, wy);

    int xs[4], ys[4];
    #pragma unroll
    for (int i = 0; i < 4; ++i) {
        xs[i] = wrap36(ix - 1 + i);
        ys[i] = wrap36(iy - 1 + i);
    }

    const float* rt = rama_tables + (size_t)ri * NBIN * NBIN;
    float er = 0.0f;
    #pragma unroll
    for (int i = 0; i < 4; ++i) {
        float rowv = 0.0f;
        const float* rrow = rt + xs[i] * NBIN;
        #pragma unroll
        for (int j = 0; j < 4; ++j) rowv += wy[j] * rrow[ys[j]];
        er += wx[i] * rowv;
    }
    float r_contrib = (tv[0] && tv[1]) ? er : 0.0f;

    // ---- omega ----
    const int oi = s_ip[btc];
    const float z = (dih[2] - s_op[oi * 2 + 0]) / s_op[oi * 2 + 1];
    const float iz0 = floorf(z);
    const float fz = z - iz0;
    const int iz = (int)iz0;
    float wz[4];
    crw(fz, wz);
    const float* ot = s_ot + oi * NBIN;
    float eo = 0.0f;
    #pragma unroll
    for (int i = 0; i < 4; ++i) eo += wz[i] * ot[wrap36(iz - 1 + i)];
    float o_contrib = tv[2] ? eo : 0.0f;

    // ---- reduce: wave64 shuffle, then across 16 waves via LDS ----
    float r = r_contrib;
    float o = o_contrib;
    #pragma unroll
    for (int d = 32; d > 0; d >>= 1) {
        r += __shfl_down(r, d);
        o += __shfl_down(o, d);
    }
    const int wid = tid >> 6;
    if ((tid & 63) == 0) {
        swr[wid] = r;
        swo[wid] = o;
    }
    __syncthreads();
    if (tid < 64) {
        float R = (tid < 16) ? swr[tid] : 0.0f;
        float O = (tid < 16) ? swo[tid] : 0.0f;
        #pragma unroll
        for (int d = 8; d > 0; d >>= 1) {
            R += __shfl_down(R, d);
            O += __shfl_down(O, d);
        }
        if (tid == 0) {
            out[p]      = R;   // direct write: no atomics, no memset needed
            out[PN + p] = O;
        }
    }
}

extern "C" void kernel_launch(void* const* d_in, const int* in_sizes, int n_in,
                              void* d_out, int out_size, void* d_ws, size_t ws_size,
                              hipStream_t stream) {
    const float* coords        = (const float*)d_in[0];
    const int*   off           = (const int*)d_in[1];
    const int*   btype         = (const int*)d_in[2];
    const int*   conn          = (const int*)d_in[3];
    const int*   dsc           = (const int*)d_in[4];
    const int*   rama_tbl_ind  = (const int*)d_in[5];
    const int*   upper_conn    = (const int*)d_in[6];
    const int*   is_pro        = (const int*)d_in[7];
    const int*   tor_atoms     = (const int*)d_in[8];
    const float* rama_tables   = (const float*)d_in[9];
    const float* omega_tables  = (const float*)d_in[10];
    const float* rama_params   = (const float*)d_in[11];
    const float* omega_params  = (const float*)d_in[12];
    float* out = (float*)d_out;

    // One block per pose; each block writes its two outputs exactly once,
    // so no memset and no atomics are needed.
    dim3 grid(PN);
    dim3 block(1024);
    bb_torsion_kernel<<<grid, block, 0, stream>>>(
        coords, off, btype, conn, dsc, rama_tbl_ind, upper_conn, is_pro,
        tor_atoms, rama_tables, omega_tables, rama_params, omega_params, out);
}